// Round 6
// baseline (382.324 us; speedup 1.0000x reference)
//
#include <hip/hip_runtime.h>

typedef unsigned short u16;
typedef __attribute__((ext_vector_type(8))) _Float16 f16x8;
typedef __attribute__((ext_vector_type(2))) __fp16 fp16v2;
typedef __attribute__((ext_vector_type(4))) float f32x4;
typedef __attribute__((ext_vector_type(16))) float f32x16;

#define T_SEQ 2048
#define NH 16
#define DH 64
#define DM 1024
// NEG * log2(e), masks applied in log2 domain (softmax via exp2)
#define NEG2 (-14426.95f)
// 64^-0.25 * sqrt(log2(e)) : folded so S^T comes out pre-scaled for exp2
#define QS2 (0.42466089f)

__device__ __forceinline__ unsigned pk2(float a, float b) {
  union { fp16v2 v; unsigned u; } c;
  c.v = __builtin_amdgcn_cvt_pkrtz(a, b);
  return c.u;
}
__device__ __forceinline__ u16 f2h(float a) {
  union { _Float16 h; u16 u; } c; c.h = (_Float16)a; return c.u;
}

__device__ __forceinline__ void async_load16(const void* g, void* l) {
  __builtin_amdgcn_global_load_lds(
      (const __attribute__((address_space(1))) unsigned int*)(g),
      (__attribute__((address_space(3))) unsigned int*)(l), 16, 0, 0);
}

// ---------------- convert fp32 -> fp16 ----------------
__global__ __launch_bounds__(256) void convert_all(
    const float* __restrict__ q, const float* __restrict__ k, const float* __restrict__ v,
    const float* __restrict__ Wq, const float* __restrict__ Wk, const float* __restrict__ Wv,
    const float* __restrict__ Wo, u16* __restrict__ xb, u16* __restrict__ wb) {
  int blk = blockIdx.x;
  const float* src; u16* dst;
  if (blk < 12288) {
    int s = blk >> 12;
    src = (s == 0) ? q : (s == 1) ? k : v;
    dst = xb + (size_t)s * 8388608u;
    blk &= 4095;
  } else {
    int s = (blk - 12288) >> 9;
    src = (s == 0) ? Wq : (s == 1) ? Wk : (s == 2) ? Wv : Wo;
    dst = wb + (size_t)s * 1048576u;
    blk = (blk - 12288) & 511;
  }
  size_t base = (size_t)blk * 2048 + (size_t)threadIdx.x * 8;
  float4 a = *(const float4*)(src + base);
  float4 b2 = *(const float4*)(src + base + 4);
  uint4 st;
  st.x = pk2(a.x, a.y); st.y = pk2(a.z, a.w);
  st.z = pk2(b2.x, b2.y); st.w = pk2(b2.z, b2.w);
  *(uint4*)(dst + base) = st;
}

// ---------------- fused QKV projection GEMM (32x32x16 MFMA) ----------------
// which = n0>>10 selects INPUT activation (q/k/v at A+which*8M), weight, output.
// which<2 (Q/K): MFMA operands SWAPPED (row dim = channel); epilogue packs
//   along row, LDS-transposes, stores [bh][t][dh] coalesced (dwordx4).
// which==2 (V): normal order (row dim = t); stores VT [bh][dh][t] coalesced.
__global__ __launch_bounds__(256) void gemm_qkv(const u16* __restrict__ A,
                                                const u16* __restrict__ Wqb,
                                                const u16* __restrict__ Wkb,
                                                const u16* __restrict__ Wvb,
                                                u16* __restrict__ Qh, u16* __restrict__ Kh,
                                                u16* __restrict__ VTh) {
  __shared__ char lds[33792];  // staging [0,32768); epilogue tile 128x264B
  const int tid = threadIdx.x;
  const int wid = tid >> 6, lane = tid & 63;
  const int l32 = lane & 31, lh = lane >> 5;
  const int m0 = blockIdx.x * 128;
  const int n0 = blockIdx.y * 128;
  const int which = n0 >> 10;
  const int n0l = n0 & 1023;
  const u16* As = A + (size_t)which * 8388608u;
  const u16* Bw = (which == 0) ? Wqb : (which == 1) ? Wkb : Wvb;
  const int wm = wid >> 1, wn = wid & 1;
  // rbase: LDS region feeding the MFMA A-operand (row dim), cbase: B-operand
  char* const rbase = (which < 2) ? (lds + 16384) : lds;       // W : X
  char* const cbase = (which < 2) ? lds : (lds + 16384);       // X : W
  f32x16 acc[2][2] = {};

  for (int kt = 0; kt < 1024; kt += 64) {
    __syncthreads();
    // cells: p = mt*4+ks; holds M[.. + mt*32 + l32][kt + ks*16 + lh*8 ..+8]
    for (int i = 0; i < 4; ++i) {
      int p = wid * 4 + i;
      int mt = p >> 2, ks = p & 3;
      int col = kt + ks * 16 + lh * 8;
      async_load16(As + (size_t)(m0 + mt * 32 + l32) * 1024 + col, lds + p * 1024);
      async_load16(Bw + (size_t)(n0l + mt * 32 + l32) * 1024 + col, lds + 16384 + p * 1024);
    }
    __syncthreads();
    for (int ks = 0; ks < 4; ++ks) {
      f16x8 rf[2], cf[2];
      for (int i = 0; i < 2; ++i) {
        rf[i] = *(const f16x8*)(rbase + ((wm * 2 + i) * 4 + ks) * 1024 + lane * 16);
        cf[i] = *(const f16x8*)(cbase + ((wn * 2 + i) * 4 + ks) * 1024 + lane * 16);
      }
      for (int i = 0; i < 2; ++i)
        for (int j = 0; j < 2; ++j)
          acc[i][j] = __builtin_amdgcn_mfma_f32_32x32x16_f16(rf[i], cf[j], acc[i][j], 0, 0, 0);
    }
  }

  // epilogue: C/D row = (reg&3)+8*(reg>>2)+4*lh, col = l32.
  // pack 4 consecutive rows (one reg group) -> uint2, LDS tile [col][row]
  const float s = (which < 2) ? QS2 : 1.0f;
  __syncthreads();
  for (int i = 0; i < 2; ++i)
    for (int j = 0; j < 2; ++j) {
      int colb = wn * 64 + j * 32 + l32;
      int rowb = wm * 64 + i * 32 + 4 * lh;
      for (int g = 0; g < 4; ++g) {
        uint2 pv;
        pv.x = pk2(acc[i][j][4 * g + 0] * s, acc[i][j][4 * g + 1] * s);
        pv.y = pk2(acc[i][j][4 * g + 2] * s, acc[i][j][4 * g + 3] * s);
        *(uint2*)(lds + colb * 264 + (rowb + 8 * g) * 2) = pv;
      }
    }
  __syncthreads();

  const int b = m0 >> 11, t0 = m0 & 2047, h0 = n0l >> 6;
  if (which < 2) {
    // LDS tile [t_local][channel]: rows = t (128), 256B of channels + pad
    u16* O = which ? Kh : Qh;
    for (int p = 0; p < 8; ++p) {
      int row = p * 16 + (tid >> 4);  // t_local
      int seg = tid & 15;
      uint4 val = *(const uint4*)(lds + row * 264 + seg * 16);
      int hl = seg >> 3, dh0 = (seg & 7) * 8;
      *(uint4*)(O + (((size_t)(b * NH + h0 + hl) * T_SEQ + t0 + row) << 6) + dh0) = val;
    }
  } else {
    // LDS tile [ch_local][t]: rows = channel (128), 256B of t + pad
    for (int p = 0; p < 8; ++p) {
      int row = p * 16 + (tid >> 4);  // ch_local
      int seg = tid & 15;
      uint4 val = *(const uint4*)(lds + row * 264 + seg * 16);
      int h = h0 + (row >> 6), dh = row & 63;
      *(uint4*)(VTh + (((size_t)(b * NH + h) * DH + dh) << 11) + t0 + seg * 8) = val;
    }
  }
}

// ---------------- output projection GEMM (32x32x16 MFMA, fp32 out) ----------------
__global__ __launch_bounds__(256) void gemm_out(const u16* __restrict__ A,
                                                const u16* __restrict__ Bw,
                                                float* __restrict__ O) {
  __shared__ char lds[32768];
  const int tid = threadIdx.x;
  const int wid = tid >> 6, lane = tid & 63;
  const int l32 = lane & 31, lh = lane >> 5;
  const int m0 = blockIdx.x * 128, n0 = blockIdx.y * 128;
  const int wm = wid >> 1, wn = wid & 1;
  f32x16 acc[2][2] = {};

  for (int kt = 0; kt < 1024; kt += 64) {
    __syncthreads();
    for (int i = 0; i < 4; ++i) {
      int p = wid * 4 + i;
      int mt = p >> 2, ks = p & 3;
      int col = kt + ks * 16 + lh * 8;
      async_load16(A + (size_t)(m0 + mt * 32 + l32) * 1024 + col, lds + p * 1024);
      async_load16(Bw + (size_t)(n0 + mt * 32 + l32) * 1024 + col, lds + 16384 + p * 1024);
    }
    __syncthreads();
    for (int ks = 0; ks < 4; ++ks) {
      f16x8 af[2], bf[2];
      for (int i = 0; i < 2; ++i) {
        af[i] = *(const f16x8*)(lds + ((wm * 2 + i) * 4 + ks) * 1024 + lane * 16);
        bf[i] = *(const f16x8*)(lds + 16384 + ((wn * 2 + i) * 4 + ks) * 1024 + lane * 16);
      }
      for (int i = 0; i < 2; ++i)
        for (int j = 0; j < 2; ++j)
          acc[i][j] = __builtin_amdgcn_mfma_f32_32x32x16_f16(af[i], bf[j], acc[i][j], 0, 0, 0);
    }
  }
  for (int i = 0; i < 2; ++i)
    for (int j = 0; j < 2; ++j) {
      int col = n0 + wn * 64 + j * 32 + l32;
      int rowb = m0 + wm * 64 + i * 32 + 4 * lh;
      for (int g = 0; g < 4; ++g)
        for (int rr = 0; rr < 4; ++rr)
          O[(size_t)(rowb + 8 * g + rr) * 1024 + col] = acc[i][j][4 * g + rr];
    }
}

// ---------------- Flash attention (S^T formulation, fp16, 8 waves) ----------------
// Qh/Kh: f16 [bh][t][64] pre-scaled by QS2. VTh: f16 [bh][dh][t].
// ctx out: f16 [b][t][1024]. Block = 512 thr, q-tile 128; pair (p8, 15-p8).
// XCD swizzle: bid = p8*64 + bh  ->  same-head blocks share XCD (bid&7 = bh&7).
__global__ __launch_bounds__(512) void attn_kernel(const u16* __restrict__ Qh,
                                                   const u16* __restrict__ Kh,
                                                   const u16* __restrict__ VTh,
                                                   const float* __restrict__ attn_mask,
                                                   const int* __restrict__ mfp,
                                                   u16* __restrict__ ctx) {
  __shared__ char kls[8192];      // K chunk (64s x 64k), cells (st*2+kk)
  __shared__ char vls[8192];      // V^T chunk (64dh x 64s), cells (nt*2+kk)
  __shared__ char pls[8][2048];   // per-wave P (16q x 64s) in A-frag order
  __shared__ float maskb[T_SEQ];  // pad bias in log2 domain
  __shared__ int mzf;             // 1 if any pad-mask zero for this b

  const int tid = threadIdx.x;
  const int wid = tid >> 6, lane = tid & 63;
  const int lm = lane & 15, lq = lane >> 4;
  const int bid = blockIdx.x;
  const int bh_i = bid & 63, p8 = bid >> 6;
  const int b = bh_i >> 4, h = bh_i & 15;
  const int mf = *mfp;
  const size_t bh = (size_t)(b * NH + h);
  const u16* Qbh = Qh + bh * T_SEQ * DH;
  const u16* Kbh = Kh + bh * T_SEQ * DH;
  const u16* VTbh = VTh + bh * DH * T_SEQ;

  if (tid == 0) mzf = 0;
  __syncthreads();
  {
    int az = 0;
    for (int i = tid; i < T_SEQ; i += 512) {
      float mv = attn_mask[(size_t)b * T_SEQ + i];
      maskb[i] = (mv == 0.0f) ? NEG2 : 0.0f;
      az |= (mv == 0.0f);
    }
    if (az) mzf = 1;  // benign same-value race
  }
  __syncthreads();
  const int maskzero = mzf;

  for (int half = 0; half < 2; ++half) {
    const int qt = half ? (15 - p8) : p8;   // 128-row q-tile index
    const int q0 = qt * 128;
    const int qw = q0 + wid * 16;
    // Q as B-operand: lane needs Q[q=qw+lm][k=kk*32+lq*8+j]
    f16x8 qf[2];
    qf[0] = *(const f16x8*)(Qbh + (size_t)(qw + lm) * DH + lq * 8);
    qf[1] = *(const f16x8*)(Qbh + (size_t)(qw + lm) * DH + 32 + lq * 8);

    f32x4 acc[4] = {};                // O: row=q_loc(lq*4+r), col=dh(nt*16+lm)
    float mprev = -1e30f, lsum = 0.f; // state for q = qw+lm (replicated over lq)

    const int nch = mf ? (qt + 1) * 2 : 32;
    for (int c = 0; c < nch; ++c) {
      const int s0 = c * 64;
      __syncthreads();
      // wave wid stages K cell wid and V cell wid (1 KB each)
      async_load16(Kbh + (size_t)(s0 + (wid >> 1) * 16 + lm) * DH + (wid & 1) * 32 + lq * 8,
                   kls + wid * 1024);
      async_load16(VTbh + (size_t)((wid >> 1) * 16 + lm) * T_SEQ + s0 + (wid & 1) * 32 + lq * 8,
                   vls + wid * 1024);
      __syncthreads();

      // S^T tiles: A=K (m=s), B=Q (n=q). sc[st]: row s_loc=lq*4+r, col q=qw+lm
      f32x4 sc[4];
      for (int st = 0; st < 4; ++st) {
        f32x4 z = {0.f, 0.f, 0.f, 0.f};
        sc[st] = z;
        for (int kk = 0; kk < 2; ++kk) {
          f16x8 kf = *(const f16x8*)(kls + ((st * 2 + kk) * 64 + lane) * 16);
          sc[st] = __builtin_amdgcn_mfma_f32_16x16x32_f16(kf, qf[kk], sc[st], 0, 0, 0);
        }
      }
      // pad bias only when the mask actually has zeros (wave-uniform skip)
      if (maskzero) {
        for (int st = 0; st < 4; ++st) {
          f32x4 mb = *(const f32x4*)(maskb + s0 + st * 16 + lq * 4);
          for (int r = 0; r < 4; ++r) sc[st][r] += mb[r];
        }
      }
      // causal: only diagonal-overlapping chunks need the compare
      if (mf && (s0 + 64 > qw)) {
        int qg = qw + lm;
        for (int st = 0; st < 4; ++st)
          for (int r = 0; r < 4; ++r)
            if (s0 + st * 16 + lq * 4 + r > qg) sc[st][r] = NEG2;
      }
      // online softmax over s: chunk max, then conditional rescale
      float mx = fmaxf(fmaxf(sc[0][0], sc[0][1]), fmaxf(sc[0][2], sc[0][3]));
      for (int st = 1; st < 4; ++st) {
        float t2 = fmaxf(fmaxf(sc[st][0], sc[st][1]), fmaxf(sc[st][2], sc[st][3]));
        mx = fmaxf(mx, t2);
      }
      mx = fmaxf(mx, __shfl_xor(mx, 16));
      mx = fmaxf(mx, __shfl_xor(mx, 32));
      float mn = mprev;
      if (__ballot(mx > mprev) != 0ull) {  // wave-uniform: any row's max grew
        mn = fmaxf(mprev, mx);
        float alpha = exp2f(mprev - mn);
        for (int r = 0; r < 4; ++r) {
          float ar = __shfl(alpha, lq * 4 + r);
          for (int nt = 0; nt < 4; ++nt) acc[nt][r] *= ar;
        }
        lsum *= alpha;
        mprev = mn;
      }
      float ps = 0.f;
      for (int st = 0; st < 4; ++st)
        for (int r = 0; r < 4; ++r) {
          float p = exp2f(sc[st][r] - mn);
          sc[st][r] = p;
          ps += p;
        }
      ps += __shfl_xor(ps, 16);
      ps += __shfl_xor(ps, 32);
      lsum += ps;
      // P -> per-wave LDS in A-frag order (packed b64 writes, pkrtz)
      {
        char* pw = pls[wid];
        for (int st = 0; st < 4; ++st) {
          int kk = st >> 1;
          int lqp = (st & 1) * 2 + (lq >> 1);
          uint2 pv;
          pv.x = pk2(sc[st][0], sc[st][1]);
          pv.y = pk2(sc[st][2], sc[st][3]);
          *(uint2*)(pw + kk * 1024 + (lqp * 16 + lm) * 16 + (lq & 1) * 8) = pv;
        }
      }
      asm volatile("s_waitcnt lgkmcnt(0)" ::: "memory");
      for (int kk = 0; kk < 2; ++kk) {
        f16x8 pf = *(const f16x8*)(pls[wid] + kk * 1024 + lane * 16);
        for (int nt = 0; nt < 4; ++nt) {
          f16x8 vf = *(const f16x8*)(vls + ((nt * 2 + kk) * 64 + lane) * 16);
          acc[nt] = __builtin_amdgcn_mfma_f32_16x16x32_f16(pf, vf, acc[nt], 0, 0, 0);
        }
      }
    }
    // epilogue: ctx[b][t][h*64+dh] f16
    float inv = 1.0f / lsum;
    for (int r = 0; r < 4; ++r) {
      float ir = __shfl(inv, lq * 4 + r);
      int t = qw + lq * 4 + r;
      for (int nt = 0; nt < 4; ++nt)
        ctx[((size_t)(b * T_SEQ + t) * DM) + h * DH + nt * 16 + lm] = f2h(acc[nt][r] * ir);
    }
  }
}

extern "C" void kernel_launch(void* const* d_in, const int* in_sizes, int n_in,
                              void* d_out, int out_size, void* d_ws, size_t ws_size,
                              hipStream_t stream) {
  const float* q = (const float*)d_in[0];
  const float* k = (const float*)d_in[1];
  const float* v = (const float*)d_in[2];
  const float* attn_mask = (const float*)d_in[3];
  const float* Wq = (const float*)d_in[4];
  const float* Wk = (const float*)d_in[5];
  const float* Wv = (const float*)d_in[6];
  const float* Wo = (const float*)d_in[7];
  const int* mf = (const int*)d_in[8];

  u16* ws = (u16*)d_ws;
  u16* qb  = ws;                      // f16 inputs [8192,1024] x3 (q,k,v contiguous)
  u16* wqb = ws + 3u * 8388608u;      // f16 weights x4
  u16* wkb = wqb + 1048576u;
  u16* wvb = wkb + 1048576u;
  u16* wob = wvb + 1048576u;
  u16* Qh  = wob + 1048576u;          // [bh][t][64]
  u16* Kh  = Qh + 8388608u;           // [bh][t][64]
  u16* VTh = Kh + 8388608u;           // [bh][dh][2048]
  u16* ctxb = ws;                     // alias over qb (dead after projections)

  convert_all<<<14336, 256, 0, stream>>>(q, k, v, Wq, Wk, Wv, Wo, qb, wqb);

  dim3 gq(64, 24);
  gemm_qkv<<<gq, 256, 0, stream>>>(qb, wqb, wkb, wvb, Qh, Kh, VTh);

  attn_kernel<<<512, 512, 0, stream>>>(Qh, Kh, VTh, attn_mask, mf, ctxb);

  dim3 gg(64, 8);
  gemm_out<<<gg, 256, 0, stream>>>(ctxb, wob, (float*)d_out);
}

// Round 7
// 375.948 us; speedup vs baseline: 1.0170x; 1.0170x over previous
//
#include <hip/hip_runtime.h>

typedef unsigned short u16;
typedef __attribute__((ext_vector_type(8))) _Float16 f16x8;
typedef __attribute__((ext_vector_type(2))) __fp16 fp16v2;
typedef __attribute__((ext_vector_type(4))) float f32x4;
typedef __attribute__((ext_vector_type(16))) float f32x16;

#define T_SEQ 2048
#define NH 16
#define DH 64
#define DM 1024
// NEG * log2(e), masks applied in log2 domain (softmax via exp2)
#define NEG2 (-14426.95f)
// 64^-0.25 * sqrt(log2(e)) : folded so S^T comes out pre-scaled for exp2
#define QS2 (0.42466089f)

__device__ __forceinline__ unsigned pk2(float a, float b) {
  union { fp16v2 v; unsigned u; } c;
  c.v = __builtin_amdgcn_cvt_pkrtz(a, b);
  return c.u;
}
__device__ __forceinline__ u16 f2h(float a) {
  union { _Float16 h; u16 u; } c; c.h = (_Float16)a; return c.u;
}

__device__ __forceinline__ void async_load16(const void* g, void* l) {
  __builtin_amdgcn_global_load_lds(
      (const __attribute__((address_space(1))) unsigned int*)(g),
      (__attribute__((address_space(3))) unsigned int*)(l), 16, 0, 0);
}

// ---------------- convert fp32 -> fp16 ----------------
__global__ __launch_bounds__(256) void convert_all(
    const float* __restrict__ q, const float* __restrict__ k, const float* __restrict__ v,
    const float* __restrict__ Wq, const float* __restrict__ Wk, const float* __restrict__ Wv,
    const float* __restrict__ Wo, u16* __restrict__ xb, u16* __restrict__ wb) {
  int blk = blockIdx.x;
  const float* src; u16* dst;
  if (blk < 12288) {
    int s = blk >> 12;
    src = (s == 0) ? q : (s == 1) ? k : v;
    dst = xb + (size_t)s * 8388608u;
    blk &= 4095;
  } else {
    int s = (blk - 12288) >> 9;
    src = (s == 0) ? Wq : (s == 1) ? Wk : (s == 2) ? Wv : Wo;
    dst = wb + (size_t)s * 1048576u;
    blk = (blk - 12288) & 511;
  }
  size_t base = (size_t)blk * 2048 + (size_t)threadIdx.x * 8;
  float4 a = *(const float4*)(src + base);
  float4 b2 = *(const float4*)(src + base + 4);
  uint4 st;
  st.x = pk2(a.x, a.y); st.y = pk2(a.z, a.w);
  st.z = pk2(b2.x, b2.y); st.w = pk2(b2.z, b2.w);
  *(uint4*)(dst + base) = st;
}

// ---------------- fused QKV projection GEMM (32x32x16 MFMA, dbuf K-loop) ----------------
// which = n0>>10 selects INPUT activation (q/k/v at A+which*8M), weight, output.
// which<2 (Q/K): MFMA operands SWAPPED (row dim = channel); epilogue packs
//   along row, LDS-transposes, stores [bh][t][dh] coalesced (dwordx4).
// which==2 (V): normal order (row dim = t); stores VT [bh][dh][t] coalesced.
// K-loop: BK=32, two 16KB buffers, ONE barrier per iter; prefetch for k+1
// issued right after the barrier so its latency overlaps tile-k compute.
__global__ __launch_bounds__(256) void gemm_qkv(const u16* __restrict__ A,
                                                const u16* __restrict__ Wqb,
                                                const u16* __restrict__ Wkb,
                                                const u16* __restrict__ Wvb,
                                                u16* __restrict__ Qh, u16* __restrict__ Kh,
                                                u16* __restrict__ VTh) {
  __shared__ char lds[33792];  // dbuf staging [0,32768); epilogue tile aliases all
  const int tid = threadIdx.x;
  const int wid = tid >> 6, lane = tid & 63;
  const int l32 = lane & 31, lh = lane >> 5;
  const int m0 = blockIdx.x * 128;
  const int n0 = blockIdx.y * 128;
  const int which = n0 >> 10;
  const int n0l = n0 & 1023;
  const u16* As = A + (size_t)which * 8388608u;
  const u16* Bw = (which == 0) ? Wqb : (which == 1) ? Wkb : Wvb;
  const int wm = wid >> 1, wn = wid & 1;
  f32x16 acc[2][2] = {};

  // cell c = mt*2+ks (1KB): M[m0+mt*32+l32][kt+ks*16+lh*8 ..+8]; wave stages mt=wid.
  const u16* gA = As + (size_t)(m0 + wid * 32 + l32) * 1024 + lh * 8;
  const u16* gB = Bw + (size_t)(n0l + wid * 32 + l32) * 1024 + lh * 8;
  // prologue: stage k-tile 0 into buffer 0
  async_load16(gA, lds + (wid * 2 + 0) * 1024);
  async_load16(gA + 16, lds + (wid * 2 + 1) * 1024);
  async_load16(gB, lds + 8192 + (wid * 2 + 0) * 1024);
  async_load16(gB + 16, lds + 8192 + (wid * 2 + 1) * 1024);

  for (int it = 0; it < 32; ++it) {
    __syncthreads();  // buf[it&1] ready; all waves done reading buf[(it-1)&1]
    char* cur = lds + (it & 1) * 16384;
    if (it < 31) {
      char* nxt = lds + ((it + 1) & 1) * 16384;
      int kt = (it + 1) * 32;
      async_load16(gA + kt, nxt + (wid * 2 + 0) * 1024);
      async_load16(gA + kt + 16, nxt + (wid * 2 + 1) * 1024);
      async_load16(gB + kt, nxt + 8192 + (wid * 2 + 0) * 1024);
      async_load16(gB + kt + 16, nxt + 8192 + (wid * 2 + 1) * 1024);
    }
    char* const rb = (which < 2) ? (cur + 8192) : cur;  // A-op: W for Q/K, X for V
    char* const cb = (which < 2) ? cur : (cur + 8192);
    for (int ks = 0; ks < 2; ++ks) {
      f16x8 rf[2], cf[2];
      for (int i = 0; i < 2; ++i) {
        rf[i] = *(const f16x8*)(rb + ((wm * 2 + i) * 2 + ks) * 1024 + lane * 16);
        cf[i] = *(const f16x8*)(cb + ((wn * 2 + i) * 2 + ks) * 1024 + lane * 16);
      }
      for (int i = 0; i < 2; ++i)
        for (int j = 0; j < 2; ++j)
          acc[i][j] = __builtin_amdgcn_mfma_f32_32x32x16_f16(rf[i], cf[j], acc[i][j], 0, 0, 0);
    }
  }

  // epilogue: C/D row = (reg&3)+8*(reg>>2)+4*lh, col = l32.
  // pack 4 consecutive rows (one reg group) -> uint2, LDS tile [col][row]
  const float s = (which < 2) ? QS2 : 1.0f;
  __syncthreads();
  for (int i = 0; i < 2; ++i)
    for (int j = 0; j < 2; ++j) {
      int colb = wn * 64 + j * 32 + l32;
      int rowb = wm * 64 + i * 32 + 4 * lh;
      for (int g = 0; g < 4; ++g) {
        uint2 pv;
        pv.x = pk2(acc[i][j][4 * g + 0] * s, acc[i][j][4 * g + 1] * s);
        pv.y = pk2(acc[i][j][4 * g + 2] * s, acc[i][j][4 * g + 3] * s);
        *(uint2*)(lds + colb * 264 + (rowb + 8 * g) * 2) = pv;
      }
    }
  __syncthreads();

  const int b = m0 >> 11, t0 = m0 & 2047, h0 = n0l >> 6;
  if (which < 2) {
    // LDS tile [t_local][channel]: rows = t (128), 256B of channels + pad
    u16* O = which ? Kh : Qh;
    for (int p = 0; p < 8; ++p) {
      int row = p * 16 + (tid >> 4);  // t_local
      int seg = tid & 15;
      uint4 val = *(const uint4*)(lds + row * 264 + seg * 16);
      int hl = seg >> 3, dh0 = (seg & 7) * 8;
      *(uint4*)(O + (((size_t)(b * NH + h0 + hl) * T_SEQ + t0 + row) << 6) + dh0) = val;
    }
  } else {
    // LDS tile [ch_local][t]: rows = channel (128), 256B of t + pad
    for (int p = 0; p < 8; ++p) {
      int row = p * 16 + (tid >> 4);  // ch_local
      int seg = tid & 15;
      uint4 val = *(const uint4*)(lds + row * 264 + seg * 16);
      int h = h0 + (row >> 6), dh = row & 63;
      *(uint4*)(VTh + (((size_t)(b * NH + h) * DH + dh) << 11) + t0 + seg * 8) = val;
    }
  }
}

// ---------------- output projection GEMM (32x32x16 MFMA, dbuf, fp32 out) ----------------
__global__ __launch_bounds__(256) void gemm_out(const u16* __restrict__ A,
                                                const u16* __restrict__ Bw,
                                                float* __restrict__ O) {
  __shared__ char lds[32768];
  const int tid = threadIdx.x;
  const int wid = tid >> 6, lane = tid & 63;
  const int l32 = lane & 31, lh = lane >> 5;
  const int m0 = blockIdx.x * 128, n0 = blockIdx.y * 128;
  const int wm = wid >> 1, wn = wid & 1;
  f32x16 acc[2][2] = {};

  const u16* gA = A + (size_t)(m0 + wid * 32 + l32) * 1024 + lh * 8;
  const u16* gB = Bw + (size_t)(n0 + wid * 32 + l32) * 1024 + lh * 8;
  async_load16(gA, lds + (wid * 2 + 0) * 1024);
  async_load16(gA + 16, lds + (wid * 2 + 1) * 1024);
  async_load16(gB, lds + 8192 + (wid * 2 + 0) * 1024);
  async_load16(gB + 16, lds + 8192 + (wid * 2 + 1) * 1024);

  for (int it = 0; it < 32; ++it) {
    __syncthreads();
    char* cur = lds + (it & 1) * 16384;
    if (it < 31) {
      char* nxt = lds + ((it + 1) & 1) * 16384;
      int kt = (it + 1) * 32;
      async_load16(gA + kt, nxt + (wid * 2 + 0) * 1024);
      async_load16(gA + kt + 16, nxt + (wid * 2 + 1) * 1024);
      async_load16(gB + kt, nxt + 8192 + (wid * 2 + 0) * 1024);
      async_load16(gB + kt + 16, nxt + 8192 + (wid * 2 + 1) * 1024);
    }
    for (int ks = 0; ks < 2; ++ks) {
      f16x8 af[2], bf[2];
      for (int i = 0; i < 2; ++i) {
        af[i] = *(const f16x8*)(cur + ((wm * 2 + i) * 2 + ks) * 1024 + lane * 16);
        bf[i] = *(const f16x8*)(cur + 8192 + ((wn * 2 + i) * 2 + ks) * 1024 + lane * 16);
      }
      for (int i = 0; i < 2; ++i)
        for (int j = 0; j < 2; ++j)
          acc[i][j] = __builtin_amdgcn_mfma_f32_32x32x16_f16(af[i], bf[j], acc[i][j], 0, 0, 0);
    }
  }
  for (int i = 0; i < 2; ++i)
    for (int j = 0; j < 2; ++j) {
      int col = n0 + wn * 64 + j * 32 + l32;
      int rowb = m0 + wm * 64 + i * 32 + 4 * lh;
      for (int g = 0; g < 4; ++g)
        for (int rr = 0; rr < 4; ++rr)
          O[(size_t)(rowb + 8 * g + rr) * 1024 + col] = acc[i][j][4 * g + rr];
    }
}

// ---------------- Flash attention (S^T formulation, fp16, 8 waves) ----------------
// Qh/Kh: f16 [bh][t][64] pre-scaled by QS2. VTh: f16 [bh][dh][t].
// ctx out: f16 [b][t][1024]. Block = 512 thr, q-tile 128; pair (p8, 15-p8).
// XCD swizzle: bid = p8*64 + bh  ->  same-head blocks share XCD (bid&7 = bh&7).
__global__ __launch_bounds__(512) void attn_kernel(const u16* __restrict__ Qh,
                                                   const u16* __restrict__ Kh,
                                                   const u16* __restrict__ VTh,
                                                   const float* __restrict__ attn_mask,
                                                   const int* __restrict__ mfp,
                                                   u16* __restrict__ ctx) {
  __shared__ char kls[8192];      // K chunk (64s x 64k), cells (st*2+kk)
  __shared__ char vls[8192];      // V^T chunk (64dh x 64s), cells (nt*2+kk)
  __shared__ char pls[8][2048];   // per-wave P (16q x 64s) in A-frag order
  __shared__ float maskb[T_SEQ];  // pad bias in log2 domain
  __shared__ int mzf;             // 1 if any pad-mask zero for this b

  const int tid = threadIdx.x;
  const int wid = tid >> 6, lane = tid & 63;
  const int lm = lane & 15, lq = lane >> 4;
  const int bid = blockIdx.x;
  const int bh_i = bid & 63, p8 = bid >> 6;
  const int b = bh_i >> 4, h = bh_i & 15;
  const int mf = *mfp;
  const size_t bh = (size_t)(b * NH + h);
  const u16* Qbh = Qh + bh * T_SEQ * DH;
  const u16* Kbh = Kh + bh * T_SEQ * DH;
  const u16* VTbh = VTh + bh * DH * T_SEQ;

  if (tid == 0) mzf = 0;
  __syncthreads();
  {
    int az = 0;
    for (int i = tid; i < T_SEQ; i += 512) {
      float mv = attn_mask[(size_t)b * T_SEQ + i];
      maskb[i] = (mv == 0.0f) ? NEG2 : 0.0f;
      az |= (mv == 0.0f);
    }
    if (az) mzf = 1;  // benign same-value race
  }
  __syncthreads();
  const int maskzero = mzf;

  for (int half = 0; half < 2; ++half) {
    const int qt = half ? (15 - p8) : p8;   // 128-row q-tile index
    const int q0 = qt * 128;
    const int qw = q0 + wid * 16;
    // Q as B-operand: lane needs Q[q=qw+lm][k=kk*32+lq*8+j]
    f16x8 qf[2];
    qf[0] = *(const f16x8*)(Qbh + (size_t)(qw + lm) * DH + lq * 8);
    qf[1] = *(const f16x8*)(Qbh + (size_t)(qw + lm) * DH + 32 + lq * 8);

    f32x4 acc[4] = {};                // O: row=q_loc(lq*4+r), col=dh(nt*16+lm)
    float mprev = -1e30f, lsum = 0.f; // state for q = qw+lm (replicated over lq)

    const int nch = mf ? (qt + 1) * 2 : 32;
    for (int c = 0; c < nch; ++c) {
      const int s0 = c * 64;
      __syncthreads();
      // wave wid stages K cell wid and V cell wid (1 KB each)
      async_load16(Kbh + (size_t)(s0 + (wid >> 1) * 16 + lm) * DH + (wid & 1) * 32 + lq * 8,
                   kls + wid * 1024);
      async_load16(VTbh + (size_t)((wid >> 1) * 16 + lm) * T_SEQ + s0 + (wid & 1) * 32 + lq * 8,
                   vls + wid * 1024);
      __syncthreads();

      // S^T tiles: A=K (m=s), B=Q (n=q). sc[st]: row s_loc=lq*4+r, col q=qw+lm
      f32x4 sc[4];
      for (int st = 0; st < 4; ++st) {
        f32x4 z = {0.f, 0.f, 0.f, 0.f};
        sc[st] = z;
        for (int kk = 0; kk < 2; ++kk) {
          f16x8 kf = *(const f16x8*)(kls + ((st * 2 + kk) * 64 + lane) * 16);
          sc[st] = __builtin_amdgcn_mfma_f32_16x16x32_f16(kf, qf[kk], sc[st], 0, 0, 0);
        }
      }
      // pad bias only when the mask actually has zeros (wave-uniform skip)
      if (maskzero) {
        for (int st = 0; st < 4; ++st) {
          f32x4 mb = *(const f32x4*)(maskb + s0 + st * 16 + lq * 4);
          for (int r = 0; r < 4; ++r) sc[st][r] += mb[r];
        }
      }
      // causal: only diagonal-overlapping chunks need the compare
      if (mf && (s0 + 64 > qw)) {
        int qg = qw + lm;
        for (int st = 0; st < 4; ++st)
          for (int r = 0; r < 4; ++r)
            if (s0 + st * 16 + lq * 4 + r > qg) sc[st][r] = NEG2;
      }
      // online softmax over s: chunk max, then conditional rescale
      float mx = fmaxf(fmaxf(sc[0][0], sc[0][1]), fmaxf(sc[0][2], sc[0][3]));
      for (int st = 1; st < 4; ++st) {
        float t2 = fmaxf(fmaxf(sc[st][0], sc[st][1]), fmaxf(sc[st][2], sc[st][3]));
        mx = fmaxf(mx, t2);
      }
      mx = fmaxf(mx, __shfl_xor(mx, 16));
      mx = fmaxf(mx, __shfl_xor(mx, 32));
      float mn = mprev;
      if (__ballot(mx > mprev) != 0ull) {  // wave-uniform: any row's max grew
        mn = fmaxf(mprev, mx);
        float alpha = exp2f(mprev - mn);
        for (int r = 0; r < 4; ++r) {
          float ar = __shfl(alpha, lq * 4 + r);
          for (int nt = 0; nt < 4; ++nt) acc[nt][r] *= ar;
        }
        lsum *= alpha;
        mprev = mn;
      }
      float ps = 0.f;
      for (int st = 0; st < 4; ++st)
        for (int r = 0; r < 4; ++r) {
          float p = exp2f(sc[st][r] - mn);
          sc[st][r] = p;
          ps += p;
        }
      ps += __shfl_xor(ps, 16);
      ps += __shfl_xor(ps, 32);
      lsum += ps;
      // P -> per-wave LDS in A-frag order (packed b64 writes, pkrtz)
      {
        char* pw = pls[wid];
        for (int st = 0; st < 4; ++st) {
          int kk = st >> 1;
          int lqp = (st & 1) * 2 + (lq >> 1);
          uint2 pv;
          pv.x = pk2(sc[st][0], sc[st][1]);
          pv.y = pk2(sc[st][2], sc[st][3]);
          *(uint2*)(pw + kk * 1024 + (lqp * 16 + lm) * 16 + (lq & 1) * 8) = pv;
        }
      }
      asm volatile("s_waitcnt lgkmcnt(0)" ::: "memory");
      for (int kk = 0; kk < 2; ++kk) {
        f16x8 pf = *(const f16x8*)(pls[wid] + kk * 1024 + lane * 16);
        for (int nt = 0; nt < 4; ++nt) {
          f16x8 vf = *(const f16x8*)(vls + ((nt * 2 + kk) * 64 + lane) * 16);
          acc[nt] = __builtin_amdgcn_mfma_f32_16x16x32_f16(pf, vf, acc[nt], 0, 0, 0);
        }
      }
    }
    // epilogue: ctx[b][t][h*64+dh] f16
    float inv = 1.0f / lsum;
    for (int r = 0; r < 4; ++r) {
      float ir = __shfl(inv, lq * 4 + r);
      int t = qw + lq * 4 + r;
      for (int nt = 0; nt < 4; ++nt)
        ctx[((size_t)(b * T_SEQ + t) * DM) + h * DH + nt * 16 + lm] = f2h(acc[nt][r] * ir);
    }
  }
}

extern "C" void kernel_launch(void* const* d_in, const int* in_sizes, int n_in,
                              void* d_out, int out_size, void* d_ws, size_t ws_size,
                              hipStream_t stream) {
  const float* q = (const float*)d_in[0];
  const float* k = (const float*)d_in[1];
  const float* v = (const float*)d_in[2];
  const float* attn_mask = (const float*)d_in[3];
  const float* Wq = (const float*)d_in[4];
  const float* Wk = (const float*)d_in[5];
  const float* Wv = (const float*)d_in[6];
  const float* Wo = (const float*)d_in[7];
  const int* mf = (const int*)d_in[8];

  u16* ws = (u16*)d_ws;
  u16* qb  = ws;                      // f16 inputs [8192,1024] x3 (q,k,v contiguous)
  u16* wqb = ws + 3u * 8388608u;      // f16 weights x4
  u16* wkb = wqb + 1048576u;
  u16* wvb = wkb + 1048576u;
  u16* wob = wvb + 1048576u;
  u16* Qh  = wob + 1048576u;          // [bh][t][64]
  u16* Kh  = Qh + 8388608u;           // [bh][t][64]
  u16* VTh = Kh + 8388608u;           // [bh][dh][2048]
  u16* ctxb = ws;                     // alias over qb (dead after projections)

  convert_all<<<14336, 256, 0, stream>>>(q, k, v, Wq, Wk, Wv, Wo, qb, wqb);

  dim3 gq(64, 24);
  gemm_qkv<<<gq, 256, 0, stream>>>(qb, wqb, wkb, wvb, Qh, Kh, VTh);

  attn_kernel<<<512, 512, 0, stream>>>(Qh, Kh, VTh, attn_mask, mf, ctxb);

  dim3 gg(64, 8);
  gemm_out<<<gg, 256, 0, stream>>>(ctxb, wob, (float*)d_out);
}